// Round 5
// baseline (138.227 us; speedup 1.0000x reference)
//
#include <hip/hip_runtime.h>

typedef unsigned long long u64;
typedef unsigned int u32;

#define N_TOT 25200
#define L0_END 19200
#define L1_END 24000
#define NCLS 80
#define CAP 512           // max boxes/class; E[M]=315, sigma~17.6 -> +11 sigma
#define NW 8              // 512 bits -> 8 u64 words
#define CNT_STRIDE 16     // ints; 64B between class counters

__device__ __constant__ float c_AW[9] = {12.f,19.f,40.f,36.f,76.f,72.f,142.f,192.f,459.f};
__device__ __constant__ float c_AH[9] = {16.f,36.f,28.f,75.f,55.f,146.f,110.f,243.f,401.f};

// ---------------- decode + bucket: 4 lanes per anchor ----------------
__global__ __launch_bounds__(256)
void decode_kernel(const float* __restrict__ p0,
                   const float* __restrict__ p1,
                   const float* __restrict__ p2,
                   int* __restrict__ cnt,
                   u64* __restrict__ bucket,
                   float* __restrict__ out)
{
    int t = blockIdx.x * 256 + threadIdx.x;
    int n = t >> 2;          // anchor
    int q = t & 3;           // lane-in-group: classes c = 4k+q
    if (n >= N_TOT) return;

    const float* p; int f, strd, base, lvl;
    if (n < L0_END)      { p = p0; f = 80; strd = 8;  base = 0;      lvl = 0; }
    else if (n < L1_END) { p = p1; f = 40; strd = 16; base = L0_END; lvl = 1; }
    else                 { p = p2; f = 20; strd = 32; base = L1_END; lvl = 2; }

    int r  = n - base;
    int hw = r / 3;
    int a  = r - hw * 3;
    int HW = f * f;
    int gx = hw % f;
    int gy = hw / f;
    const float* cell = p + hw;
    const float* clsp = cell + (3 + a * NCLS) * HW;

    // hoist leader-only loads: issue early, consume after softmax (latency overlap)
    float obj = 0.f, tx = 0.f, ty = 0.f, tw = 0.f, th = 0.f;
    if (q == 0) {
        obj = cell[a * HW];
        const float* regp = cell + (243 + a * 4) * HW;
        tx = regp[0];
        ty = regp[HW];
        tw = regp[2 * HW];
        th = regp[3 * HW];
    }

    float v[20];
    #pragma unroll
    for (int k = 0; k < 20; ++k) v[k] = clsp[(4 * k + q) * HW];

    float lmax = v[0];
    #pragma unroll
    for (int k = 1; k < 20; ++k) lmax = fmaxf(lmax, v[k]);
    float gm = lmax;
    gm = fmaxf(gm, __shfl_xor(gm, 1));
    gm = fmaxf(gm, __shfl_xor(gm, 2));

    float ls = 0.f, bp = -1.f; int ba_ = 0;
    #pragma unroll
    for (int k = 0; k < 20; ++k) {
        float pc = expf(v[k] - gm);
        ls += pc;
        if (pc > bp) { bp = pc; ba_ = 4 * k + q; }
    }
    float gs = ls;
    gs += __shfl_xor(gs, 1);
    gs += __shfl_xor(gs, 2);
    {
        float bp2 = __shfl_xor(bp, 1); int ba2 = __shfl_xor(ba_, 1);
        if (bp2 > bp || (bp2 == bp && ba2 < ba_)) { bp = bp2; ba_ = ba2; }
        bp2 = __shfl_xor(bp, 2); ba2 = __shfl_xor(ba_, 2);
        if (bp2 > bp || (bp2 == bp && ba2 < ba_)) { bp = bp2; ba_ = ba2; }
    }

    if (q != 0) return;                            // leader finishes the anchor

    float sig  = 1.f / (1.f + expf(-obj));
    float conf = sig * (bp / gs);

    // bucket valid boxes per class (key: conf desc, then idx asc via ~idx)
    if (conf >= 0.001f) {                          // == (conf_f32 >= 0.001 as f64)
        int pos = atomicAdd(&cnt[ba_ * CNT_STRIDE], 1);
        if (pos < CAP)
            bucket[ba_ * CAP + pos] = ((u64)__float_as_uint(conf) << 32) | (u64)(~(u32)n);
    }

    float sx = 1.f / (1.f + expf(-tx));
    float sy = 1.f / (1.f + expf(-ty));
    float cx = (sx + (float)gx) * (float)strd;
    float cy = (sy + (float)gy) * (float)strd;
    int ai = lvl * 3 + a;
    float w  = expf(tw) * c_AW[ai];
    float h  = expf(th) * c_AH[ai];
    float hx = w * 0.5f, hy = h * 0.5f;
    float x1 = (cx - hx) / 640.0f;
    float y1 = (cy - hy) / 640.0f;
    float x2 = (cx + hx) / 640.0f;
    float y2 = (cy + hy) / 640.0f;
    x1 = fminf(fmaxf(x1, 0.f), 1.f);
    y1 = fminf(fmaxf(y1, 0.f), 1.f);
    x2 = fminf(fmaxf(x2, 0.f), 1.f);
    y2 = fminf(fmaxf(y2, 0.f), 1.f);

    *(float4*)(out + n * 4) = make_float4(x1, y1, x2, y2);
    out[100800 + n] = conf;
    out[126000 + n] = (float)ba_;
    out[151200 + n] = 0.0f;                        // keep default
}

// ------------- per-class NMS: sort + kill-set build + ctz/readlane scan -------------
__global__ __launch_bounds__(512)
void nms_kernel(const int* __restrict__ cnt,
                const u64* __restrict__ bucket,
                const float* __restrict__ bboxes,   // = d_out (clipped boxes)
                float* __restrict__ out_keep)
{
    const int c = blockIdx.x;
    const int tid = threadIdx.x;
    const int wave = tid >> 6, lane = tid & 63;

    __shared__ u64   skey[CAP];          // 4 KB
    __shared__ float4 sbox[CAP + 1];     // 8.2 KB (+1: prefetch pad)
    __shared__ float  sar[CAP + 1];      // 2 KB
    __shared__ int    sgi[CAP];          // 2 KB
    __shared__ u64    colT[CAP * NW];    // 32 KB: colT[i*8+cw] = {j in chunk cw : j>i, IoU(i,j)>=0.6}
    __shared__ u32    sup32[NW * 2];     // incoming suppression per chunk (lo,hi)

    const int M = min(cnt[c * CNT_STRIDE], CAP);
    if (tid < NW * 2) sup32[tid] = 0u;

    u64 ke = 0;
    if (tid < M) { ke = bucket[c * CAP + tid]; skey[tid] = ke; }
    __syncthreads();

    // rank sort (conf desc, idx asc; unique keys) + scatter sorted offset boxes
    if (tid < M) {
        int rank = 0;
        int j = 0;
        for (; j + 4 <= M; j += 4) {
            u64 a0 = skey[j], a1 = skey[j+1], a2 = skey[j+2], a3 = skey[j+3];
            rank += (int)(a0 > ke) + (int)(a1 > ke) + (int)(a2 > ke) + (int)(a3 > ke);
        }
        for (; j < M; ++j) rank += (int)(skey[j] > ke);

        u32 gi = ~(u32)ke;
        const float4 b = *(const float4*)(bboxes + gi * 4);
        float off = 4.0f * (float)c;             // ref computes IoU on class-offset boxes
        float x1 = b.x + off, y1 = b.y + off, x2 = b.z + off, y2 = b.w + off;
        sbox[rank] = make_float4(x1, y1, x2, y2);
        sar[rank]  = (x2 - x1) * (y2 - y1);
        sgi[rank]  = (int)gi;
    }
    __syncthreads();

    // build kill-sets: tile (rw<=cw); lane = row i (regs), cols broadcast+prefetched
    const int MW = (M + 63) >> 6;
    const int ntiles = (MW * (MW + 1)) >> 1;
    for (int t = wave; t < ntiles; t += 8) {
        int rw = 0, acc = 0;
        while (t >= acc + (MW - rw)) { acc += MW - rw; ++rw; }
        const int cw = rw + (t - acc);
        const int i  = (rw << 6) + lane;
        const float4 bb = sbox[i];
        const float  ban = sar[i];
        const int c0 = cw << 6;
        const int c1 = min(c0 + 64, M);
        float4 nb = sbox[c0]; float na = sar[c0];
        u64 bits = 0ull;
        for (int j = c0; j < c1; ++j) {
            float4 cb = nb; float ca = na;
            nb = sbox[j + 1]; na = sar[j + 1];          // prefetch (pad slot at [512])
            float xx1 = fmaxf(bb.x, cb.x);
            float yy1 = fmaxf(bb.y, cb.y);
            float xx2 = fminf(bb.z, cb.z);
            float yy2 = fminf(bb.w, cb.w);
            float ww = fmaxf(1e-28f, xx2 - xx1);
            float hh = fmaxf(1e-28f, yy2 - yy1);
            float inter = ww * hh;
            float ovr = inter / (ban + ca - inter + 1e-14f);  // same op order as ref
            bits |= (u64)((i < j) && (ovr >= 0.6f)) << (j & 63);
        }
        colT[i * NW + cw] = bits;   // rows i>=M hold garbage; guarded by valid/kept masks
    }
    __syncthreads();

    if (wave != 0) return;          // single-wave scan; no further barriers

    // greedy scan, tile by tile; cand/kept are wave-uniform u64s
    u64 cr[NW];
#define PROP(w, W2)                                                            \
    if ((W2) > (w) && (W2) < MW) {                                             \
        atomicOr(&sup32[2 * (W2)],     (u32)(cr[W2] & 0xffffffffull));         \
        atomicOr(&sup32[2 * (W2) + 1], (u32)(cr[W2] >> 32));                   \
    }
#define TILE(w)                                                                \
    if ((w) < MW) {                                                            \
        const int ii = ((w) << 6) + lane;                                      \
        cr[0] = colT[ii * NW + 0]; cr[1] = colT[ii * NW + 1];                  \
        cr[2] = colT[ii * NW + 2]; cr[3] = colT[ii * NW + 3];                  \
        cr[4] = colT[ii * NW + 4]; cr[5] = colT[ii * NW + 5];                  \
        cr[6] = colT[ii * NW + 6]; cr[7] = colT[ii * NW + 7];                  \
        u64 supw = ((u64)sup32[2 * (w) + 1] << 32) | (u64)sup32[2 * (w)];      \
        int rem = M - ((w) << 6);                                              \
        u64 valid = (rem >= 64) ? ~0ull : ((1ull << rem) - 1ull);              \
        u64 cand = valid & ~supw;                                              \
        u64 kept = 0ull;                                                       \
        while (cand) {                                                         \
            int b = __builtin_ctzll(cand);       /* lowest index = best rank */\
            kept |= 1ull << b;                                                 \
            u64 ks = __shfl(cr[w], b);           /* kill-set of kept box b  */ \
            cand &= ~(ks | (1ull << b));                                       \
        }                                                                      \
        if ((kept >> lane) & 1ull) {                                           \
            out_keep[sgi[ii]] = 1.0f;                                          \
            PROP(w, 1) PROP(w, 2) PROP(w, 3) PROP(w, 4)                        \
            PROP(w, 5) PROP(w, 6) PROP(w, 7)                                   \
        }                                                                      \
    }
    TILE(0) TILE(1) TILE(2) TILE(3) TILE(4) TILE(5) TILE(6) TILE(7)
#undef TILE
#undef PROP
}

extern "C" void kernel_launch(void* const* d_in, const int* in_sizes, int n_in,
                              void* d_out, int out_size, void* d_ws, size_t ws_size,
                              hipStream_t stream) {
    const float* p0 = (const float*)d_in[0];
    const float* p1 = (const float*)d_in[1];
    const float* p2 = (const float*)d_in[2];
    float* out = (float*)d_out;

    char* ws = (char*)d_ws;
    int* cnt    = (int*)ws;                      // 80*16 ints = 5120 B (zeroed each launch)
    u64* bucket = (u64*)(ws + 5120);             // 80*512*8 = 327680 B  (total 332800 B)

    hipMemsetAsync(cnt, 0, NCLS * CNT_STRIDE * sizeof(int), stream);
    decode_kernel<<<(N_TOT * 4 + 255) / 256, 256, 0, stream>>>(p0, p1, p2, cnt, bucket, out);
    nms_kernel<<<NCLS, 512, 0, stream>>>(cnt, bucket, out, out + 151200);
}

// Round 6
// 72.758 us; speedup vs baseline: 1.8998x; 1.8998x over previous
//
#include <hip/hip_runtime.h>

typedef unsigned long long u64;
typedef unsigned int u32;

#define N_TOT 25200
#define NCLS 80
#define CAP 512           // max boxes/class; E[M]=315, sigma~17.6 -> +11 sigma
#define NW 8              // 512 bits -> 8 u64 words
#define CNT_STRIDE 16     // ints; 64B between class counters
#define STRIDE_ST 72      // LDS row stride (72%32==8 -> 2-way bank alias, free)

__device__ __constant__ float c_AW[9] = {12.f,19.f,40.f,36.f,76.f,72.f,142.f,192.f,459.f};
__device__ __constant__ float c_AH[9] = {16.f,36.f,28.f,75.f,55.f,146.f,110.f,243.f,401.f};

// -------- decode: block = 64 hw-cells, coalesced LDS stage, 4 lanes/anchor --------
__global__ __launch_bounds__(256)
void decode_kernel(const float* __restrict__ p0,
                   const float* __restrict__ p1,
                   const float* __restrict__ p2,
                   int* __restrict__ cnt,
                   u64* __restrict__ bucket,
                   float* __restrict__ out)
{
    const int bid = blockIdx.x;
    const float* p; int f, strd, base, hw0, lvl;
    if (bid < 100)      { p = p0; f = 80; strd = 8;  base = 0;     hw0 = bid * 64;         lvl = 0; }
    else if (bid < 125) { p = p1; f = 40; strd = 16; base = 19200; hw0 = (bid - 100) * 64; lvl = 1; }
    else                { p = p2; f = 20; strd = 32; base = 24000; hw0 = (bid - 125) * 64; lvl = 2; }
    const int HW = f * f;

    __shared__ float st[85][STRIDE_ST];     // 24.5 KB

    const int tid = threadIdx.x;
    const int g = tid >> 2, q = tid & 3;    // group g handles cell hw0+g; lane q: classes 4k+q
    const int cell = hw0 + g;
    const bool cv = (cell < HW);
    const int gx = cv ? (cell % f) : 0;
    const int gy = cv ? (cell / f) : 0;

    for (int a = 0; a < 3; ++a) {
        // stage 85 channels x 64 cells, fully coalesced (row uniform per wave)
        for (int idx = tid; idx < 85 * 64; idx += 256) {
            int row = idx >> 6, pos = idx & 63;
            int ch;
            if (row == 0)       ch = a;                     // obj
            else if (row <= 80) ch = 3 + 80 * a + row - 1;  // cls
            else                ch = 243 + 4 * a + row - 81;// reg
            int hp = hw0 + pos;
            float val = (hp < HW) ? p[ch * HW + hp] : 0.f;
            st[row][pos] = val;
        }
        __syncthreads();

        if (cv) {
            float v[20];
            #pragma unroll
            for (int k = 0; k < 20; ++k) v[k] = st[1 + 4 * k + q][g];

            float lmax = v[0];
            #pragma unroll
            for (int k = 1; k < 20; ++k) lmax = fmaxf(lmax, v[k]);
            float gm = lmax;
            gm = fmaxf(gm, __shfl_xor(gm, 1));
            gm = fmaxf(gm, __shfl_xor(gm, 2));

            float ls = 0.f, bp = -1.f; int ba_ = 0;
            #pragma unroll
            for (int k = 0; k < 20; ++k) {
                float pc = expf(v[k] - gm);
                ls += pc;
                if (pc > bp) { bp = pc; ba_ = 4 * k + q; }
            }
            float gs = ls;
            gs += __shfl_xor(gs, 1);
            gs += __shfl_xor(gs, 2);
            {
                float bp2 = __shfl_xor(bp, 1); int ba2 = __shfl_xor(ba_, 1);
                if (bp2 > bp || (bp2 == bp && ba2 < ba_)) { bp = bp2; ba_ = ba2; }
                bp2 = __shfl_xor(bp, 2); ba2 = __shfl_xor(ba_, 2);
                if (bp2 > bp || (bp2 == bp && ba2 < ba_)) { bp = bp2; ba_ = ba2; }
            }

            if (q == 0) {
                float obj = st[0][g];
                float tx = st[81][g];
                float ty = st[82][g];
                float tw = st[83][g];
                float th = st[84][g];

                float sig  = 1.f / (1.f + expf(-obj));
                float conf = sig * (bp / gs);
                int n = base + cell * 3 + a;

                if (conf >= 0.001f) {          // == (conf_f32 >= 0.001 as f64)
                    int pos = atomicAdd(&cnt[ba_ * CNT_STRIDE], 1);
                    if (pos < CAP)
                        bucket[ba_ * CAP + pos] = ((u64)__float_as_uint(conf) << 32) | (u64)(~(u32)n);
                }

                float sx = 1.f / (1.f + expf(-tx));
                float sy = 1.f / (1.f + expf(-ty));
                float cx = (sx + (float)gx) * (float)strd;
                float cy = (sy + (float)gy) * (float)strd;
                int ai = lvl * 3 + a;
                float w  = expf(tw) * c_AW[ai];
                float h  = expf(th) * c_AH[ai];
                float hx = w * 0.5f, hy = h * 0.5f;
                float x1 = (cx - hx) / 640.0f;
                float y1 = (cy - hy) / 640.0f;
                float x2 = (cx + hx) / 640.0f;
                float y2 = (cy + hy) / 640.0f;
                x1 = fminf(fmaxf(x1, 0.f), 1.f);
                y1 = fminf(fmaxf(y1, 0.f), 1.f);
                x2 = fminf(fmaxf(x2, 0.f), 1.f);
                y2 = fminf(fmaxf(y2, 0.f), 1.f);

                *(float4*)(out + n * 4) = make_float4(x1, y1, x2, y2);
                out[100800 + n] = conf;
                out[126000 + n] = (float)ba_;
                out[151200 + n] = 0.0f;        // keep default
            }
        }
        __syncthreads();   // st reused next anchor
    }
}

// ---- per-class NMS: sort + ballot build (incoming masks) + lane-owned scan ----
__global__ __launch_bounds__(1024)
void nms_kernel(const int* __restrict__ cnt,
                const u64* __restrict__ bucket,
                const float* __restrict__ bboxes,   // = d_out (clipped boxes)
                float* __restrict__ out_keep)
{
    const int c = blockIdx.x;
    const int tid = threadIdx.x;
    const int wave = tid >> 6, lane = tid & 63;

    __shared__ u64    skey[CAP];         // 4 KB
    __shared__ float4 sbox[CAP + 1];     // 8.2 KB (+1 prefetch pad)
    __shared__ float  sar[CAP + 1];      // 2 KB
    __shared__ int    sgi[CAP];          // 2 KB
    __shared__ u64    maskT[NW * CAP];   // 32 KB: maskT[w*CAP+j] = {i in word w : i<j, IoU>=0.6}

    const int M = min(cnt[c * CNT_STRIDE], CAP);

    u64 ke = 0;
    if (tid < M) { ke = bucket[c * CAP + tid]; skey[tid] = ke; }
    __syncthreads();

    // rank sort (conf desc, idx asc; keys unique) + scatter sorted offset boxes
    if (tid < M) {
        int rank = 0;
        int j = 0;
        for (; j + 4 <= M; j += 4) {
            u64 a0 = skey[j], a1 = skey[j+1], a2 = skey[j+2], a3 = skey[j+3];
            rank += (int)(a0 > ke) + (int)(a1 > ke) + (int)(a2 > ke) + (int)(a3 > ke);
        }
        for (; j < M; ++j) rank += (int)(skey[j] > ke);

        u32 gi = ~(u32)ke;
        const float4 b = *(const float4*)(bboxes + gi * 4);
        float off = 4.0f * (float)c;             // ref computes IoU on class-offset boxes
        float x1 = b.x + off, y1 = b.y + off, x2 = b.z + off, y2 = b.w + off;
        sbox[rank] = make_float4(x1, y1, x2, y2);
        sar[rank]  = (x2 - x1) * (y2 - y1);
        sgi[rank]  = (int)gi;
    }
    __syncthreads();

    // build incoming masks: tile (rw<=cw); lane = row i (box in regs), cols broadcast
    const int MW = (M + 63) >> 6;
    const int ntiles = (MW * (MW + 1)) >> 1;
    for (int t = wave; t < ntiles; t += 16) {
        int rw = 0, acc = 0;
        while (t >= acc + (MW - rw)) { acc += MW - rw; ++rw; }
        const int cw = rw + (t - acc);
        const int i  = (rw << 6) + lane;
        const bool iv = (i < M);
        const float4 bb = sbox[i];
        const float  ban = sar[i];
        const int c0 = cw << 6;
        const int c1 = min(c0 + 64, M);
        float4 nb = sbox[c0]; float na = sar[c0];
        for (int j = c0; j < c1; ++j) {
            float4 cb = nb; float ca = na;
            nb = sbox[j + 1]; na = sar[j + 1];          // prefetch (pad slot)
            float xx1 = fmaxf(bb.x, cb.x);
            float yy1 = fmaxf(bb.y, cb.y);
            float xx2 = fminf(bb.z, cb.z);
            float yy2 = fminf(bb.w, cb.w);
            float ww = fmaxf(1e-28f, xx2 - xx1);
            float hh = fmaxf(1e-28f, yy2 - yy1);
            float inter = ww * hh;
            float ovr = inter / (ban + ca - inter + 1e-14f);  // same op order as ref
            u64 bal = __ballot(iv && (i < j) && (ovr >= 0.6f));
            if (lane == 0) maskT[rw * CAP + j] = bal;
        }
    }
    __syncthreads();

    if (wave != 0) return;      // short serial scan on wave 0 only

    u64 k0 = 0, k1 = 0, k2 = 0, k3 = 0, k4 = 0, k5 = 0, k6 = 0, k7 = 0;
    (void)k7;
#define MT(W) maskT[(W) * CAP + j]
#define TILE(W, PRE)                                                    \
    if ((W) < MW) {                                                     \
        const int j = ((W) << 6) + lane;                                \
        const u64 mine = MT(W);                                         \
        const u64 pre = (PRE);                                          \
        const int rem = M - ((W) << 6);                                 \
        const u64 valid = (rem >= 64) ? ~0ull : ((1ull << rem) - 1ull); \
        u64 cand = valid & ~__ballot(pre != 0ull);                      \
        u64 kept = 0ull;                                                \
        while (cand) {                                                  \
            const int b = __builtin_ctzll(cand);                        \
            kept |= 1ull << b;                                          \
            const u64 row = __ballot((mine >> b) & 1ull);               \
            cand &= ~(row | (1ull << b));                               \
        }                                                               \
        k##W = kept;                                                    \
        if ((kept >> lane) & 1ull) out_keep[sgi[j]] = 1.0f;             \
    }
    TILE(0, 0ull)
    TILE(1, (MT(0)&k0))
    TILE(2, (MT(0)&k0)|(MT(1)&k1))
    TILE(3, (MT(0)&k0)|(MT(1)&k1)|(MT(2)&k2))
    TILE(4, (MT(0)&k0)|(MT(1)&k1)|(MT(2)&k2)|(MT(3)&k3))
    TILE(5, (MT(0)&k0)|(MT(1)&k1)|(MT(2)&k2)|(MT(3)&k3)|(MT(4)&k4))
    TILE(6, (MT(0)&k0)|(MT(1)&k1)|(MT(2)&k2)|(MT(3)&k3)|(MT(4)&k4)|(MT(5)&k5))
    TILE(7, (MT(0)&k0)|(MT(1)&k1)|(MT(2)&k2)|(MT(3)&k3)|(MT(4)&k4)|(MT(5)&k5)|(MT(6)&k6))
#undef TILE
#undef MT
}

extern "C" void kernel_launch(void* const* d_in, const int* in_sizes, int n_in,
                              void* d_out, int out_size, void* d_ws, size_t ws_size,
                              hipStream_t stream) {
    const float* p0 = (const float*)d_in[0];
    const float* p1 = (const float*)d_in[1];
    const float* p2 = (const float*)d_in[2];
    float* out = (float*)d_out;

    char* ws = (char*)d_ws;
    int* cnt    = (int*)ws;                      // 80*16 ints = 5120 B (zeroed each launch)
    u64* bucket = (u64*)(ws + 5120);             // 80*512*8 = 327680 B

    hipMemsetAsync(cnt, 0, NCLS * CNT_STRIDE * sizeof(int), stream);
    decode_kernel<<<132, 256, 0, stream>>>(p0, p1, p2, cnt, bucket, out);
    nms_kernel<<<NCLS, 1024, 0, stream>>>(cnt, bucket, out, out + 151200);
}

// Round 7
// 64.401 us; speedup vs baseline: 2.1464x; 1.1298x over previous
//
#include <hip/hip_runtime.h>

typedef unsigned long long u64;
typedef unsigned int u32;

#define NCLS 80
#define CAP 512           // max boxes/class; E[M]=315, sigma~17.6 -> +11 sigma
#define CNT_STRIDE 16     // ints; 64B between class counters
#define ST_STRIDE 72      // LDS row stride (72%32==8 -> 2-way bank alias, free)

__device__ __constant__ float c_AW[9] = {12.f,19.f,40.f,36.f,76.f,72.f,142.f,192.f,459.f};
__device__ __constant__ float c_AH[9] = {16.f,36.f,28.f,75.f,55.f,146.f,110.f,243.f,401.f};

// ---- decode: block = (64-cell tile, anchor a); register-batched stage; 4 lanes/anchor ----
__global__ __launch_bounds__(256)
void decode_kernel(const float* __restrict__ p0,
                   const float* __restrict__ p1,
                   const float* __restrict__ p2,
                   int* __restrict__ cnt,
                   u64* __restrict__ bucket,
                   float* __restrict__ out)
{
    const int bid = blockIdx.x;
    const float* p; int f, strd, base, lvl, rem;
    if (bid < 300)      { p = p0; f = 80; strd = 8;  base = 0;     lvl = 0; rem = bid; }
    else if (bid < 375) { p = p1; f = 40; strd = 16; base = 19200; lvl = 1; rem = bid - 300; }
    else                { p = p2; f = 20; strd = 32; base = 24000; lvl = 2; rem = bid - 375; }
    const int a    = rem % 3;
    const int tile = rem / 3;
    const int HW   = f * f;
    const int hw0  = tile << 6;

    __shared__ float st[85][ST_STRIDE];     // 24.5 KB

    const int tid = threadIdx.x;
    const int lane = tid & 63, wv = tid >> 6;

    // stage 85 rows x 64 cells: each wave does rows {wv, wv+4, ...}; 22 loads batched in regs
    {
        const int hp = min(hw0 + lane, HW - 1);      // clamp: edge garbage discarded by cv guard
        float vals[22];
        #pragma unroll
        for (int k = 0; k < 22; ++k) {
            const int row = wv + 4 * k;
            if (row < 85) {
                const int ch = (row == 0) ? a
                             : (row <= 80 ? (3 + 80 * a + (row - 1))
                                          : (243 + 4 * a + (row - 81)));
                vals[k] = p[ch * HW + hp];
            }
        }
        #pragma unroll
        for (int k = 0; k < 22; ++k) {
            const int row = wv + 4 * k;
            if (row < 85) st[row][lane] = vals[k];
        }
    }
    __syncthreads();

    const int g = tid >> 2, q = tid & 3;    // group g = cell, lane q: classes 4k+q
    const int cell = hw0 + g;
    if (cell >= HW) return;                 // no barrier after this point
    const int gx = cell % f;
    const int gy = cell / f;

    float v[20];
    #pragma unroll
    for (int k = 0; k < 20; ++k) v[k] = st[1 + 4 * k + q][g];

    float lmax = v[0];
    #pragma unroll
    for (int k = 1; k < 20; ++k) lmax = fmaxf(lmax, v[k]);
    float gm = lmax;
    gm = fmaxf(gm, __shfl_xor(gm, 1));
    gm = fmaxf(gm, __shfl_xor(gm, 2));

    float ls = 0.f, bp = -1.f; int ba_ = 0;
    #pragma unroll
    for (int k = 0; k < 20; ++k) {
        float pc = expf(v[k] - gm);
        ls += pc;
        if (pc > bp) { bp = pc; ba_ = 4 * k + q; }
    }
    float gs = ls;
    gs += __shfl_xor(gs, 1);
    gs += __shfl_xor(gs, 2);
    {
        float bp2 = __shfl_xor(bp, 1); int ba2 = __shfl_xor(ba_, 1);
        if (bp2 > bp || (bp2 == bp && ba2 < ba_)) { bp = bp2; ba_ = ba2; }
        bp2 = __shfl_xor(bp, 2); ba2 = __shfl_xor(ba_, 2);
        if (bp2 > bp || (bp2 == bp && ba2 < ba_)) { bp = bp2; ba_ = ba2; }
    }

    if (q != 0) return;                     // leader finishes the anchor

    float obj = st[0][g];
    float tx = st[81][g];
    float ty = st[82][g];
    float tw = st[83][g];
    float th = st[84][g];

    float sig  = 1.f / (1.f + expf(-obj));
    float conf = sig * (bp / gs);
    const int n = base + cell * 3 + a;

    if (conf >= 0.001f) {                   // == (conf_f32 >= 0.001 as f64)
        int pos = atomicAdd(&cnt[ba_ * CNT_STRIDE], 1);
        if (pos < CAP)
            bucket[ba_ * CAP + pos] = ((u64)__float_as_uint(conf) << 32) | (u64)(~(u32)n);
    }

    float sx = 1.f / (1.f + expf(-tx));
    float sy = 1.f / (1.f + expf(-ty));
    float cx = (sx + (float)gx) * (float)strd;
    float cy = (sy + (float)gy) * (float)strd;
    const int ai = lvl * 3 + a;
    float w  = expf(tw) * c_AW[ai];
    float h  = expf(th) * c_AH[ai];
    float hx = w * 0.5f, hy = h * 0.5f;
    float x1 = (cx - hx) / 640.0f;
    float y1 = (cy - hy) / 640.0f;
    float x2 = (cx + hx) / 640.0f;
    float y2 = (cy + hy) / 640.0f;
    x1 = fminf(fmaxf(x1, 0.f), 1.f);
    y1 = fminf(fmaxf(y1, 0.f), 1.f);
    x2 = fminf(fmaxf(x2, 0.f), 1.f);
    y2 = fminf(fmaxf(y2, 0.f), 1.f);

    *(float4*)(out + n * 4) = make_float4(x1, y1, x2, y2);
    out[100800 + n] = conf;
    out[126000 + n] = (float)ba_;
    out[151200 + n] = 0.0f;                 // keep default
}

// ---- per-class NMS: scalar-key sort + col-in-reg build + lane-owned scan ----
__global__ __launch_bounds__(1024)
void nms_kernel(const int* __restrict__ cnt,
                const u64* __restrict__ bucket,
                const float* __restrict__ bboxes,   // = d_out (clipped boxes)
                float* __restrict__ out_keep)
{
    const int c = blockIdx.x;
    const int tid = threadIdx.x;
    const int wave = tid >> 6, lane = tid & 63;

    __shared__ float4 sbox[CAP + 1];     // 8.2 KB (+1 prefetch pad)
    __shared__ int    sgi[CAP];          // 2 KB
    __shared__ u64    maskT[8 * CAP];    // 32 KB: maskT[w*CAP+j] = {i in word w : i<j, IoU>=0.6}

    const int M  = min(cnt[c * CNT_STRIDE], CAP);
    const int MW = (M + 63) >> 6;
    const u64* kb = bucket + c * CAP;

    // rank sort (conf desc, idx asc; keys unique): waves 0..MW-1 only.
    // key stream via wave-uniform global reads (SMEM/L2, no DS pipe traffic)
    if (wave < MW) {
        const int e = (wave << 6) + lane;
        if (e < M) {
            const u64 ke = kb[e];                    // per-lane coalesced
            int rank = 0;
            int j = 0;
            for (; j + 8 <= M; j += 8) {
                rank += (int)(kb[j]   > ke) + (int)(kb[j+1] > ke)
                      + (int)(kb[j+2] > ke) + (int)(kb[j+3] > ke)
                      + (int)(kb[j+4] > ke) + (int)(kb[j+5] > ke)
                      + (int)(kb[j+6] > ke) + (int)(kb[j+7] > ke);
            }
            for (; j < M; ++j) rank += (int)(kb[j] > ke);

            const u32 gi = ~(u32)ke;
            const float4 b = *(const float4*)(bboxes + gi * 4);
            const float off = 4.0f * (float)c;       // ref computes IoU on class-offset boxes
            sbox[rank] = make_float4(b.x + off, b.y + off, b.z + off, b.w + off);
            sgi[rank]  = (int)gi;
        }
    }
    __syncthreads();

    // build incoming masks: tile (rw<=cw); lane = COLUMN j (box in regs), rows broadcast;
    // each lane accumulates its own mask word -> one ds_write_b64 (stride 8B, conflict-free)
    const int ntiles = (MW * (MW + 1)) >> 1;
    for (int t = wave; t < ntiles; t += 16) {
        int rw = 0, acc = 0;
        while (t >= acc + (MW - rw)) { acc += MW - rw; ++rw; }
        const int cw = rw + (t - acc);
        const int j  = (cw << 6) + lane;
        const float4 cb = sbox[min(j, M - 1)];       // j>=M lanes: garbage, never read in scan
        const float  ca = (cb.z - cb.x) * (cb.w - cb.y);
        const int r0 = rw << 6;
        const int r1 = min(r0 + 64, M);
        u64 bits = 0ull;
        float4 nb = sbox[r0];
        for (int i = r0; i < r1; ++i) {
            const float4 rb = nb;
            nb = sbox[i + 1];                        // broadcast prefetch (pad slot)
            const float ra = (rb.z - rb.x) * (rb.w - rb.y);   // identical expr to ref areas
            float xx1 = fmaxf(rb.x, cb.x);
            float yy1 = fmaxf(rb.y, cb.y);
            float xx2 = fminf(rb.z, cb.z);
            float yy2 = fminf(rb.w, cb.w);
            float ww = fmaxf(1e-28f, xx2 - xx1);
            float hh = fmaxf(1e-28f, yy2 - yy1);
            float inter = ww * hh;
            float ovr = inter / (ra + ca - inter + 1e-14f);   // areas[i]+areas[j], ref order
            bits |= (u64)((i < j) && (ovr >= 0.6f)) << (i & 63);
        }
        maskT[rw * CAP + j] = bits;
    }
    __syncthreads();

    if (wave != 0) return;      // short serial scan on wave 0 only

    u64 k0 = 0, k1 = 0, k2 = 0, k3 = 0, k4 = 0, k5 = 0, k6 = 0, k7 = 0;
    (void)k7;
#define MT(W) maskT[(W) * CAP + j]
#define TILE(W, PRE)                                                    \
    if ((W) < MW) {                                                     \
        const int j = ((W) << 6) + lane;                                \
        const u64 mine = MT(W);                                         \
        const u64 pre = (PRE);                                          \
        const int rm = M - ((W) << 6);                                  \
        const u64 valid = (rm >= 64) ? ~0ull : ((1ull << rm) - 1ull);   \
        u64 cand = valid & ~__ballot(pre != 0ull);                      \
        u64 kept = 0ull;                                                \
        while (cand) {                                                  \
            const int b = __builtin_ctzll(cand);                        \
            kept |= 1ull << b;                                          \
            const u64 row = __ballot((mine >> b) & 1ull);               \
            cand &= ~(row | (1ull << b));                               \
        }                                                               \
        k##W = kept;                                                    \
        if ((kept >> lane) & 1ull) out_keep[sgi[j]] = 1.0f;             \
    }
    TILE(0, 0ull)
    TILE(1, (MT(0)&k0))
    TILE(2, (MT(0)&k0)|(MT(1)&k1))
    TILE(3, (MT(0)&k0)|(MT(1)&k1)|(MT(2)&k2))
    TILE(4, (MT(0)&k0)|(MT(1)&k1)|(MT(2)&k2)|(MT(3)&k3))
    TILE(5, (MT(0)&k0)|(MT(1)&k1)|(MT(2)&k2)|(MT(3)&k3)|(MT(4)&k4))
    TILE(6, (MT(0)&k0)|(MT(1)&k1)|(MT(2)&k2)|(MT(3)&k3)|(MT(4)&k4)|(MT(5)&k5))
    TILE(7, (MT(0)&k0)|(MT(1)&k1)|(MT(2)&k2)|(MT(3)&k3)|(MT(4)&k4)|(MT(5)&k5)|(MT(6)&k6))
#undef TILE
#undef MT
}

extern "C" void kernel_launch(void* const* d_in, const int* in_sizes, int n_in,
                              void* d_out, int out_size, void* d_ws, size_t ws_size,
                              hipStream_t stream) {
    const float* p0 = (const float*)d_in[0];
    const float* p1 = (const float*)d_in[1];
    const float* p2 = (const float*)d_in[2];
    float* out = (float*)d_out;

    char* ws = (char*)d_ws;
    int* cnt    = (int*)ws;                      // 80*16 ints = 5120 B (zeroed each launch)
    u64* bucket = (u64*)(ws + 5120);             // 80*512*8 = 327680 B

    hipMemsetAsync(cnt, 0, NCLS * CNT_STRIDE * sizeof(int), stream);
    decode_kernel<<<396, 256, 0, stream>>>(p0, p1, p2, cnt, bucket, out);
    nms_kernel<<<NCLS, 1024, 0, stream>>>(cnt, bucket, out, out + 151200);
}

// Round 8
// 51.918 us; speedup vs baseline: 2.6624x; 1.2404x over previous
//
#include <hip/hip_runtime.h>

typedef unsigned long long u64;
typedef unsigned int u32;

#define NCLS 80
#define CAP 512           // max boxes/class; E[M]=315, sigma~17.6 -> +11 sigma
#define CNT_STRIDE 16     // ints; 64B between class counters
#define ST_STRIDE 36      // LDS row stride for 32-cell tiles (36%32==4 -> <=2-way alias, free)

__device__ __constant__ float c_AW[9] = {12.f,19.f,40.f,36.f,76.f,72.f,142.f,192.f,459.f};
__device__ __constant__ float c_AH[9] = {16.f,36.f,28.f,75.f,55.f,146.f,110.f,243.f,401.f};

// ---- decode: block = (32-cell tile, anchor a); register-batched stage; 4 lanes/anchor ----
__global__ __launch_bounds__(128)
void decode_kernel(const float* __restrict__ p0,
                   const float* __restrict__ p1,
                   const float* __restrict__ p2,
                   int* __restrict__ cnt,
                   u64* __restrict__ bucket,
                   float* __restrict__ out)
{
    const int bid = blockIdx.x;
    const float* p; int f, strd, base, lvl, rem;
    if (bid < 600)      { p = p0; f = 80; strd = 8;  base = 0;     lvl = 0; rem = bid; }
    else if (bid < 750) { p = p1; f = 40; strd = 16; base = 19200; lvl = 1; rem = bid - 600; }
    else                { p = p2; f = 20; strd = 32; base = 24000; lvl = 2; rem = bid - 750; }
    const int a    = rem % 3;
    const int tile = rem / 3;
    const int HW   = f * f;
    const int hw0  = tile << 5;

    __shared__ float st[88][ST_STRIDE];     // 12.4 KB

    const int tid = threadIdx.x;

    // stage 85 rows x 32 cells: thread (tid>>5 = row-quarter, tid&31 = cell); 22 loads in regs
    {
        const int col = tid & 31;
        const int r0  = tid >> 5;
        const int hp  = min(hw0 + col, HW - 1);      // clamp: edge garbage discarded by cv guard
        float vals[22];
        #pragma unroll
        for (int k = 0; k < 22; ++k) {
            const int row = r0 + 4 * k;
            if (row < 85) {
                const int ch = (row == 0) ? a
                             : (row <= 80 ? (3 + 80 * a + (row - 1))
                                          : (243 + 4 * a + (row - 81)));
                vals[k] = p[ch * HW + hp];
            }
        }
        #pragma unroll
        for (int k = 0; k < 22; ++k) {
            const int row = r0 + 4 * k;
            if (row < 85) st[row][col] = vals[k];
        }
    }
    __syncthreads();

    const int g = tid >> 2, q = tid & 3;    // group g = cell, lane q: classes 4k+q
    const int cell = hw0 + g;
    if (cell >= HW) return;                 // no barrier after this point
    const int gx = cell % f;
    const int gy = cell / f;

    float v[20];
    #pragma unroll
    for (int k = 0; k < 20; ++k) v[k] = st[1 + 4 * k + q][g];

    float lmax = v[0];
    #pragma unroll
    for (int k = 1; k < 20; ++k) lmax = fmaxf(lmax, v[k]);
    float gm = lmax;
    gm = fmaxf(gm, __shfl_xor(gm, 1));
    gm = fmaxf(gm, __shfl_xor(gm, 2));

    float ls = 0.f, bp = -1.f; int ba_ = 0;
    #pragma unroll
    for (int k = 0; k < 20; ++k) {
        float pc = expf(v[k] - gm);
        ls += pc;
        if (pc > bp) { bp = pc; ba_ = 4 * k + q; }
    }
    float gs = ls;
    gs += __shfl_xor(gs, 1);
    gs += __shfl_xor(gs, 2);
    {
        float bp2 = __shfl_xor(bp, 1); int ba2 = __shfl_xor(ba_, 1);
        if (bp2 > bp || (bp2 == bp && ba2 < ba_)) { bp = bp2; ba_ = ba2; }
        bp2 = __shfl_xor(bp, 2); ba2 = __shfl_xor(ba_, 2);
        if (bp2 > bp || (bp2 == bp && ba2 < ba_)) { bp = bp2; ba_ = ba2; }
    }

    if (q != 0) return;                     // leader finishes the anchor

    float obj = st[0][g];
    float tx = st[81][g];
    float ty = st[82][g];
    float tw = st[83][g];
    float th = st[84][g];

    float sig  = 1.f / (1.f + expf(-obj));
    float conf = sig * (bp / gs);
    const int n = base + cell * 3 + a;

    if (conf >= 0.001f) {                   // == (conf_f32 >= 0.001 as f64)
        int pos = atomicAdd(&cnt[ba_ * CNT_STRIDE], 1);
        if (pos < CAP)
            bucket[ba_ * CAP + pos] = ((u64)__float_as_uint(conf) << 32) | (u64)(~(u32)n);
    }

    float sx = 1.f / (1.f + expf(-tx));
    float sy = 1.f / (1.f + expf(-ty));
    float cx = (sx + (float)gx) * (float)strd;
    float cy = (sy + (float)gy) * (float)strd;
    const int ai = lvl * 3 + a;
    float w  = expf(tw) * c_AW[ai];
    float h  = expf(th) * c_AH[ai];
    float hx = w * 0.5f, hy = h * 0.5f;
    float x1 = (cx - hx) / 640.0f;
    float y1 = (cy - hy) / 640.0f;
    float x2 = (cx + hx) / 640.0f;
    float y2 = (cy + hy) / 640.0f;
    x1 = fminf(fmaxf(x1, 0.f), 1.f);
    y1 = fminf(fmaxf(y1, 0.f), 1.f);
    x2 = fminf(fmaxf(x2, 0.f), 1.f);
    y2 = fminf(fmaxf(y2, 0.f), 1.f);

    *(float4*)(out + n * 4) = make_float4(x1, y1, x2, y2);
    out[100800 + n] = conf;
    out[126000 + n] = (float)ba_;
    out[151200 + n] = 0.0f;                 // keep default
}

// ---- per-class NMS: scalar-key sort + col-in-reg build + frontier fixpoint scan ----
__global__ __launch_bounds__(1024)
void nms_kernel(const int* __restrict__ cnt,
                const u64* __restrict__ bucket,
                const float* __restrict__ bboxes,   // = d_out (clipped boxes)
                float* __restrict__ out_keep)
{
    const int c = blockIdx.x;
    const int tid = threadIdx.x;
    const int wave = tid >> 6, lane = tid & 63;

    __shared__ float4 sbox[CAP + 1];     // 8.2 KB (+1 prefetch pad)
    __shared__ int    sgi[CAP];          // 2 KB
    __shared__ u64    maskT[8 * CAP];    // 32 KB: maskT[w*CAP+j] = {i in word w : i<j, IoU>=0.6}

    const int M  = min(cnt[c * CNT_STRIDE], CAP);
    const int MW = (M + 63) >> 6;
    const u64* kb = bucket + c * CAP;

    // rank sort (conf desc, idx asc; keys unique): waves 0..MW-1 only
    if (wave < MW) {
        const int e = (wave << 6) + lane;
        if (e < M) {
            const u64 ke = kb[e];                    // per-lane coalesced
            int rank = 0;
            int j = 0;
            for (; j + 8 <= M; j += 8) {
                rank += (int)(kb[j]   > ke) + (int)(kb[j+1] > ke)
                      + (int)(kb[j+2] > ke) + (int)(kb[j+3] > ke)
                      + (int)(kb[j+4] > ke) + (int)(kb[j+5] > ke)
                      + (int)(kb[j+6] > ke) + (int)(kb[j+7] > ke);
            }
            for (; j < M; ++j) rank += (int)(kb[j] > ke);

            const u32 gi = ~(u32)ke;
            const float4 b = *(const float4*)(bboxes + gi * 4);
            const float off = 4.0f * (float)c;       // ref computes IoU on class-offset boxes
            sbox[rank] = make_float4(b.x + off, b.y + off, b.z + off, b.w + off);
            sgi[rank]  = (int)gi;
        }
    }
    __syncthreads();

    // build incoming masks: tile (rw<=cw); lane = COLUMN j (box in regs), rows broadcast;
    // each lane accumulates its own mask word -> one ds_write_b64 (stride 8B, conflict-free)
    const int ntiles = (MW * (MW + 1)) >> 1;
    for (int t = wave; t < ntiles; t += 16) {
        int rw = 0, acc = 0;
        while (t >= acc + (MW - rw)) { acc += MW - rw; ++rw; }
        const int cw = rw + (t - acc);
        const int j  = (cw << 6) + lane;
        const float4 cb = sbox[min(j, M - 1)];       // j>=M lanes: garbage, never read in scan
        const float  ca = (cb.z - cb.x) * (cb.w - cb.y);
        const int r0 = rw << 6;
        const int r1 = min(r0 + 64, M);
        u64 bits = 0ull;
        float4 nb = sbox[r0];
        for (int i = r0; i < r1; ++i) {
            const float4 rb = nb;
            nb = sbox[i + 1];                        // broadcast prefetch (pad slot)
            const float ra = (rb.z - rb.x) * (rb.w - rb.y);   // identical expr to ref areas
            float xx1 = fmaxf(rb.x, cb.x);
            float yy1 = fmaxf(rb.y, cb.y);
            float xx2 = fminf(rb.z, cb.z);
            float yy2 = fminf(rb.w, cb.w);
            float ww = fmaxf(1e-28f, xx2 - xx1);
            float hh = fmaxf(1e-28f, yy2 - yy1);
            float inter = ww * hh;
            float ovr = inter / (ra + ca - inter + 1e-14f);   // areas[i]+areas[j], ref order
            bits |= (u64)((i < j) && (ovr >= 0.6f)) << (i & 63);
        }
        maskT[rw * CAP + j] = bits;
    }
    __syncthreads();

    if (wave != 0) return;      // frontier scan on wave 0 only (now O(chain depth))

    u64 k0 = 0, k1 = 0, k2 = 0, k3 = 0, k4 = 0, k5 = 0, k6 = 0, k7 = 0;
    (void)k7;
#define MT(W) maskT[(W) * CAP + j]
    // Frontier fixpoint == sequential greedy:
    //  rem:  suppressed by a DECIDED keeper (only kept boxes suppress)
    //  newk: no live potential suppressor remains (all earlier edges from removed boxes)
    // Lowest cand bit always resolves (its mine has no cand bits below) -> progress.
#define TILE(W, PRE)                                                    \
    if ((W) < MW) {                                                     \
        const int j = ((W) << 6) + lane;                                \
        const u64 mine = MT(W);                                         \
        const u64 pre = (PRE);                                          \
        const int rm = M - ((W) << 6);                                  \
        const u64 valid = (rm >= 64) ? ~0ull : ((1ull << rm) - 1ull);   \
        u64 cand = valid & ~__ballot(pre != 0ull);                      \
        u64 kept = 0ull;                                                \
        while (cand) {                                                  \
            const u64 remv = cand & __ballot((mine & kept) != 0ull);    \
            cand &= ~remv;                                              \
            const u64 newk = cand & __ballot((mine & cand) == 0ull);    \
            kept |= newk;                                               \
            cand &= ~newk;                                              \
        }                                                               \
        k##W = kept;                                                    \
        if ((kept >> lane) & 1ull) out_keep[sgi[j]] = 1.0f;             \
    }
    TILE(0, 0ull)
    TILE(1, (MT(0)&k0))
    TILE(2, (MT(0)&k0)|(MT(1)&k1))
    TILE(3, (MT(0)&k0)|(MT(1)&k1)|(MT(2)&k2))
    TILE(4, (MT(0)&k0)|(MT(1)&k1)|(MT(2)&k2)|(MT(3)&k3))
    TILE(5, (MT(0)&k0)|(MT(1)&k1)|(MT(2)&k2)|(MT(3)&k3)|(MT(4)&k4))
    TILE(6, (MT(0)&k0)|(MT(1)&k1)|(MT(2)&k2)|(MT(3)&k3)|(MT(4)&k4)|(MT(5)&k5))
    TILE(7, (MT(0)&k0)|(MT(1)&k1)|(MT(2)&k2)|(MT(3)&k3)|(MT(4)&k4)|(MT(5)&k5)|(MT(6)&k6))
#undef TILE
#undef MT
}

extern "C" void kernel_launch(void* const* d_in, const int* in_sizes, int n_in,
                              void* d_out, int out_size, void* d_ws, size_t ws_size,
                              hipStream_t stream) {
    const float* p0 = (const float*)d_in[0];
    const float* p1 = (const float*)d_in[1];
    const float* p2 = (const float*)d_in[2];
    float* out = (float*)d_out;

    char* ws = (char*)d_ws;
    int* cnt    = (int*)ws;                      // 80*16 ints = 5120 B (zeroed each launch)
    u64* bucket = (u64*)(ws + 5120);             // 80*512*8 = 327680 B

    hipMemsetAsync(cnt, 0, NCLS * CNT_STRIDE * sizeof(int), stream);
    decode_kernel<<<789, 128, 0, stream>>>(p0, p1, p2, cnt, bucket, out);
    nms_kernel<<<NCLS, 1024, 0, stream>>>(cnt, bucket, out, out + 151200);
}

// Round 9
// 44.547 us; speedup vs baseline: 3.1030x; 1.1655x over previous
//
#include <hip/hip_runtime.h>

typedef unsigned long long u64;
typedef unsigned int u32;

#define NCLS 80
#define CAP 512           // max boxes/class; E[M]=315, sigma~17.6 -> +11 sigma
#define ST_STRIDE 36      // LDS row stride for 32-cell tiles (36%32==4 -> <=2-way alias, free)

__device__ __constant__ float c_AW[9] = {12.f,19.f,40.f,36.f,76.f,72.f,142.f,192.f,459.f};
__device__ __constant__ float c_AH[9] = {16.f,36.f,28.f,75.f,55.f,146.f,110.f,243.f,401.f};

// ---- decode: block = (32-cell tile, anchor a); register-batched stage; 4 lanes/anchor ----
__global__ __launch_bounds__(128)
void decode_kernel(const float* __restrict__ p0,
                   const float* __restrict__ p1,
                   const float* __restrict__ p2,
                   float* __restrict__ out)
{
    const int bid = blockIdx.x;
    const float* p; int f, strd, base, lvl, rem;
    if (bid < 600)      { p = p0; f = 80; strd = 8;  base = 0;     lvl = 0; rem = bid; }
    else if (bid < 750) { p = p1; f = 40; strd = 16; base = 19200; lvl = 1; rem = bid - 600; }
    else                { p = p2; f = 20; strd = 32; base = 24000; lvl = 2; rem = bid - 750; }
    const int a    = rem % 3;
    const int tile = rem / 3;
    const int HW   = f * f;
    const int hw0  = tile << 5;

    __shared__ float st[88][ST_STRIDE];     // 12.4 KB

    const int tid = threadIdx.x;

    // stage 85 rows x 32 cells: thread (tid>>5 = row-quarter, tid&31 = cell); 22 loads in regs
    {
        const int col = tid & 31;
        const int r0  = tid >> 5;
        const int hp  = min(hw0 + col, HW - 1);      // clamp: edge garbage discarded by cv guard
        float vals[22];
        #pragma unroll
        for (int k = 0; k < 22; ++k) {
            const int row = r0 + 4 * k;
            if (row < 85) {
                const int ch = (row == 0) ? a
                             : (row <= 80 ? (3 + 80 * a + (row - 1))
                                          : (243 + 4 * a + (row - 81)));
                vals[k] = p[ch * HW + hp];
            }
        }
        #pragma unroll
        for (int k = 0; k < 22; ++k) {
            const int row = r0 + 4 * k;
            if (row < 85) st[row][col] = vals[k];
        }
    }
    __syncthreads();

    const int g = tid >> 2, q = tid & 3;    // group g = cell, lane q: classes 4k+q
    const int cell = hw0 + g;
    if (cell >= HW) return;                 // no barrier after this point
    const int gx = cell % f;
    const int gy = cell / f;

    float v[20];
    #pragma unroll
    for (int k = 0; k < 20; ++k) v[k] = st[1 + 4 * k + q][g];

    float lmax = v[0];
    #pragma unroll
    for (int k = 1; k < 20; ++k) lmax = fmaxf(lmax, v[k]);
    float gm = lmax;
    gm = fmaxf(gm, __shfl_xor(gm, 1));
    gm = fmaxf(gm, __shfl_xor(gm, 2));

    float ls = 0.f, bp = -1.f; int ba_ = 0;
    #pragma unroll
    for (int k = 0; k < 20; ++k) {
        float pc = expf(v[k] - gm);
        ls += pc;
        if (pc > bp) { bp = pc; ba_ = 4 * k + q; }  // strict > : first max wins (np.argmax)
    }
    float gs = ls;
    gs += __shfl_xor(gs, 1);
    gs += __shfl_xor(gs, 2);
    {
        float bp2 = __shfl_xor(bp, 1); int ba2 = __shfl_xor(ba_, 1);
        if (bp2 > bp || (bp2 == bp && ba2 < ba_)) { bp = bp2; ba_ = ba2; }
        bp2 = __shfl_xor(bp, 2); ba2 = __shfl_xor(ba_, 2);
        if (bp2 > bp || (bp2 == bp && ba2 < ba_)) { bp = bp2; ba_ = ba2; }
    }

    if (q != 0) return;                     // leader finishes the anchor

    float obj = st[0][g];
    float tx = st[81][g];
    float ty = st[82][g];
    float tw = st[83][g];
    float th = st[84][g];

    float sig  = 1.f / (1.f + expf(-obj));
    float conf = sig * (bp / gs);
    const int n = base + cell * 3 + a;

    float sx = 1.f / (1.f + expf(-tx));
    float sy = 1.f / (1.f + expf(-ty));
    float cx = (sx + (float)gx) * (float)strd;
    float cy = (sy + (float)gy) * (float)strd;
    const int ai = lvl * 3 + a;
    float w  = expf(tw) * c_AW[ai];
    float h  = expf(th) * c_AH[ai];
    float hx = w * 0.5f, hy = h * 0.5f;
    float x1 = (cx - hx) / 640.0f;
    float y1 = (cy - hy) / 640.0f;
    float x2 = (cx + hx) / 640.0f;
    float y2 = (cy + hy) / 640.0f;
    x1 = fminf(fmaxf(x1, 0.f), 1.f);
    y1 = fminf(fmaxf(y1, 0.f), 1.f);
    x2 = fminf(fmaxf(x2, 0.f), 1.f);
    y2 = fminf(fmaxf(y2, 0.f), 1.f);

    *(float4*)(out + n * 4) = make_float4(x1, y1, x2, y2);
    out[100800 + n] = conf;
    out[126000 + n] = (float)ba_;
    out[151200 + n] = 0.0f;                 // keep default
}

// ---- per-class NMS: gather-from-out + LDS-key sort + col-in-reg build + fixpoint scan ----
__global__ __launch_bounds__(1024)
void nms_kernel(const float* __restrict__ out,      // full output buffer (read conf/cls/boxes)
                float* __restrict__ out_keep)
{
    const int c = blockIdx.x;
    const int tid = threadIdx.x;
    const int wave = tid >> 6, lane = tid & 63;

    __shared__ int    scnt;
    __shared__ u64    skey[CAP];         // 4 KB
    __shared__ float4 sbox[CAP + 1];     // 8.2 KB (+1 prefetch pad)
    __shared__ int    sgi[CAP];          // 2 KB
    __shared__ u64    maskT[8 * CAP];    // 32 KB: maskT[w*CAP+j] = {i in word w : i<j, IoU>=0.6}

    if (tid == 0) scnt = 0;
    __syncthreads();

    // gather this class's valid boxes straight from d_out (conf @100800, cls @126000)
    const float* confp = out + 100800;
    const float* clsp  = out + 126000;
    for (int ib = tid; ib < 6300; ib += 1024) {      // 25200/4; float4 loads, 16B-aligned
        const float4 cf4 = *(const float4*)(confp + ib * 4);
        const float4 cl4 = *(const float4*)(clsp  + ib * 4);
        #pragma unroll
        for (int k = 0; k < 4; ++k) {
            const float cf = (k == 0) ? cf4.x : (k == 1) ? cf4.y : (k == 2) ? cf4.z : cf4.w;
            const float cl = (k == 0) ? cl4.x : (k == 1) ? cl4.y : (k == 2) ? cl4.z : cl4.w;
            if ((int)cl == c && cf >= 0.001f) {      // == (cf_f32 >= 0.001 as f64)
                const int i = ib * 4 + k;
                const int pos = atomicAdd(&scnt, 1);
                if (pos < CAP)
                    skey[pos] = ((u64)__float_as_uint(cf) << 32) | (u64)(~(u32)i);
            }
        }
    }
    __syncthreads();
    const int M  = min(scnt, CAP);
    const int MW = (M + 63) >> 6;

    // rank sort (conf desc, idx asc; keys unique): waves 0..MW-1; broadcast LDS reads x8
    if (wave < MW) {
        const int e = (wave << 6) + lane;
        if (e < M) {
            const u64 ke = skey[e];
            int rank = 0;
            int j = 0;
            for (; j + 8 <= M; j += 8) {
                rank += (int)(skey[j]   > ke) + (int)(skey[j+1] > ke)
                      + (int)(skey[j+2] > ke) + (int)(skey[j+3] > ke)
                      + (int)(skey[j+4] > ke) + (int)(skey[j+5] > ke)
                      + (int)(skey[j+6] > ke) + (int)(skey[j+7] > ke);
            }
            for (; j < M; ++j) rank += (int)(skey[j] > ke);

            const u32 gi = ~(u32)ke;
            const float4 b = *(const float4*)(out + gi * 4);
            const float off = 4.0f * (float)c;       // ref computes IoU on class-offset boxes
            sbox[rank] = make_float4(b.x + off, b.y + off, b.z + off, b.w + off);
            sgi[rank]  = (int)gi;
        }
    }
    __syncthreads();

    // build incoming masks: tile (rw<=cw); lane = COLUMN j (box in regs), rows broadcast;
    // each lane accumulates its own mask word -> one ds_write_b64 (stride 8B, conflict-free)
    const int ntiles = (MW * (MW + 1)) >> 1;
    for (int t = wave; t < ntiles; t += 16) {
        int rw = 0, acc = 0;
        while (t >= acc + (MW - rw)) { acc += MW - rw; ++rw; }
        const int cw = rw + (t - acc);
        const int j  = (cw << 6) + lane;
        const float4 cb = sbox[min(j, M - 1)];       // j>=M lanes: garbage, never read in scan
        const float  ca = (cb.z - cb.x) * (cb.w - cb.y);
        const int r0 = rw << 6;
        const int r1 = min(r0 + 64, M);
        u64 bits = 0ull;
        float4 nb = sbox[r0];
        for (int i = r0; i < r1; ++i) {
            const float4 rb = nb;
            nb = sbox[i + 1];                        // broadcast prefetch (pad slot)
            const float ra = (rb.z - rb.x) * (rb.w - rb.y);   // identical expr to ref areas
            float xx1 = fmaxf(rb.x, cb.x);
            float yy1 = fmaxf(rb.y, cb.y);
            float xx2 = fminf(rb.z, cb.z);
            float yy2 = fminf(rb.w, cb.w);
            float ww = fmaxf(1e-28f, xx2 - xx1);
            float hh = fmaxf(1e-28f, yy2 - yy1);
            float inter = ww * hh;
            float ovr = inter / (ra + ca - inter + 1e-14f);   // areas[i]+areas[j], ref order
            bits |= (u64)((i < j) && (ovr >= 0.6f)) << (i & 63);
        }
        maskT[rw * CAP + j] = bits;
    }
    __syncthreads();

    if (wave != 0) return;      // frontier fixpoint scan on wave 0 (O(chain depth))

    u64 k0 = 0, k1 = 0, k2 = 0, k3 = 0, k4 = 0, k5 = 0, k6 = 0, k7 = 0;
    (void)k7;
#define MT(W) maskT[(W) * CAP + j]
    // Frontier fixpoint == sequential greedy:
    //  remv: suppressed by a DECIDED keeper (only kept boxes suppress)
    //  newk: no live potential suppressor remains
    // Lowest cand bit always resolves -> guaranteed progress.
#define TILE(W, PRE)                                                    \
    if ((W) < MW) {                                                     \
        const int j = ((W) << 6) + lane;                                \
        const u64 mine = MT(W);                                         \
        const u64 pre = (PRE);                                          \
        const int rm = M - ((W) << 6);                                  \
        const u64 valid = (rm >= 64) ? ~0ull : ((1ull << rm) - 1ull);   \
        u64 cand = valid & ~__ballot(pre != 0ull);                      \
        u64 kept = 0ull;                                                \
        while (cand) {                                                  \
            const u64 remv = cand & __ballot((mine & kept) != 0ull);    \
            cand &= ~remv;                                              \
            const u64 newk = cand & __ballot((mine & cand) == 0ull);    \
            kept |= newk;                                               \
            cand &= ~newk;                                              \
        }                                                               \
        k##W = kept;                                                    \
        if ((kept >> lane) & 1ull) out_keep[sgi[j]] = 1.0f;             \
    }
    TILE(0, 0ull)
    TILE(1, (MT(0)&k0))
    TILE(2, (MT(0)&k0)|(MT(1)&k1))
    TILE(3, (MT(0)&k0)|(MT(1)&k1)|(MT(2)&k2))
    TILE(4, (MT(0)&k0)|(MT(1)&k1)|(MT(2)&k2)|(MT(3)&k3))
    TILE(5, (MT(0)&k0)|(MT(1)&k1)|(MT(2)&k2)|(MT(3)&k3)|(MT(4)&k4))
    TILE(6, (MT(0)&k0)|(MT(1)&k1)|(MT(2)&k2)|(MT(3)&k3)|(MT(4)&k4)|(MT(5)&k5))
    TILE(7, (MT(0)&k0)|(MT(1)&k1)|(MT(2)&k2)|(MT(3)&k3)|(MT(4)&k4)|(MT(5)&k5)|(MT(6)&k6))
#undef TILE
#undef MT
}

extern "C" void kernel_launch(void* const* d_in, const int* in_sizes, int n_in,
                              void* d_out, int out_size, void* d_ws, size_t ws_size,
                              hipStream_t stream) {
    const float* p0 = (const float*)d_in[0];
    const float* p1 = (const float*)d_in[1];
    const float* p2 = (const float*)d_in[2];
    float* out = (float*)d_out;

    decode_kernel<<<789, 128, 0, stream>>>(p0, p1, p2, out);
    nms_kernel<<<NCLS, 1024, 0, stream>>>(out, out + 151200);
}